// Round 8
// baseline (185.772 us; speedup 1.0000x reference)
//
#include <hip/hip_runtime.h>
#include <hip/hip_bf16.h>

// Problem constants
#define BB 8
#define TT 2048
#define EE 1024
#define HH 64

typedef __attribute__((ext_vector_type(8))) short short8;
typedef __attribute__((ext_vector_type(4))) float f32x4;

__device__ inline f32x4 mfma_16x16x32(short8 a, short8 b, f32x4 c) {
  return __builtin_amdgcn_mfma_f32_16x16x32_bf16(a, b, c, 0, 0, 0);
}

__device__ inline short f2bf(float f) {
  __hip_bfloat16 h = __float2bfloat16(f);
  return *reinterpret_cast<short*>(&h);
}
__device__ inline float bf2f(short s) {
  __hip_bfloat16 h = *reinterpret_cast<__hip_bfloat16*>(&s);
  return __bfloat162float(h);
}

// wait lgkmcnt(0) only; leave vmcnt/expcnt unconstrained
#define WAIT_LGKM0() __builtin_amdgcn_s_waitcnt(0xC07F)

// ---------------------------------------------------------------------------
// Kernel 0: split-precision transposed weights. Block 0 also zeroes maxk2.
// ---------------------------------------------------------------------------
__global__ void prep_w(const float* __restrict__ Wq, const float* __restrict__ Wk,
                       const float* __restrict__ Wv,
                       __hip_bfloat16* __restrict__ Wthi,
                       __hip_bfloat16* __restrict__ Wtlo,
                       float* __restrict__ maxk2) {
  const int n = blockIdx.x;          // 0..191
  if (n == 0 && threadIdx.x < 8) maxk2[threadIdx.x] = 0.f;
  const int m = n >> 6;
  const int h = n & 63;
  const float* W = (m == 0) ? Wq : (m == 1) ? Wk : Wv;
  const int e0 = threadIdx.x * 4;    // 256 threads * 4 = 1024
#pragma unroll
  for (int j = 0; j < 4; ++j) {
    const float w = W[(e0 + j) * 64 + h];
    const __hip_bfloat16 hi = __float2bfloat16(w);
    Wthi[n * 1024 + e0 + j] = hi;
    Wtlo[n * 1024 + e0 + j] = __float2bfloat16(w - __bfloat162float(hi));
  }
}

// ---------------------------------------------------------------------------
// Kernel A v3: barrier-free register-direct split-bf16 GEMM + fused knorm.
// v2 post-mortem: 48us with all pipes <15% -- barrier-locked serial chain
// (16 chunks x {loads -> s_waitcnt(0) full drain -> write_A -> syncthreads}).
// v3 mirrors the attn structure that cured the same disease: each wave is
// INDEPENDENT -- loads its own A-frags (x fp32 -> hi/lo split in regs; 4x
// redundancy absorbed by L2/L3) and B-frags straight from Wthi/Wtlo (the v2
// LDS XOR-swizzle read reduces algebraically to Wthi[n*1024+c*64+l4*8]).
// Double-buffered 1.5-chunk lookahead; NO syncthreads in loop, NO LDS tile,
// NO waitcnt(0) drains, NO bank conflicts. Epilogue: same output writes +
// fused per-batch max|k_row|^2 (512B LDS + 1 barrier + 1 atomicMax/block)
// -> knorm kernel and its ~20us launch gap deleted.
// lb(256,2): 256-VGPR cap, est ~220 live. Spill tripwire = WRITE_SIZE.
// ---------------------------------------------------------------------------
__global__ __launch_bounds__(256, 2) void qkv_gemm(
    const float* __restrict__ x,
    const __hip_bfloat16* __restrict__ Wthi, const __hip_bfloat16* __restrict__ Wtlo,
    __hip_bfloat16* __restrict__ qhi, __hip_bfloat16* __restrict__ qlo,
    __hip_bfloat16* __restrict__ khi, __hip_bfloat16* __restrict__ klo,
    __hip_bfloat16* __restrict__ vT, float* __restrict__ maxk2) {
  __shared__ float Ksm[4][32];

  const int tid  = threadIdx.x;
  const int wave = tid >> 6;
  const int lane = tid & 63;
  const int l15 = lane & 15, l4 = lane >> 4;
  const int row0 = blockIdx.x * 32;

  // Wave w owns output col-groups j = {w, w+4, w+8} (q, k, v stripes).
  const __hip_bfloat16* bq_h = Wthi + ((wave)     * 16 + l15) * 1024;
  const __hip_bfloat16* bk_h = Wthi + ((wave + 4) * 16 + l15) * 1024;
  const __hip_bfloat16* bv_h = Wthi + ((wave + 8) * 16 + l15) * 1024;
  const __hip_bfloat16* bq_l = Wtlo + ((wave)     * 16 + l15) * 1024;
  const __hip_bfloat16* bk_l = Wtlo + ((wave + 4) * 16 + l15) * 1024;
  const float* xr0 = x + (size_t)(row0 + l15) * 1024;       // m=0 rows
  const float* xr1 = x + (size_t)(row0 + 16 + l15) * 1024;  // m=1 rows

  f32x4 acc[2][3];
#pragma unroll
  for (int m = 0; m < 2; ++m)
#pragma unroll
    for (int j = 0; j < 3; ++j) acc[m][j] = f32x4{0.f, 0.f, 0.f, 0.f};

  // A fp32 loads: xa[m*4 + half*2 + {0,1}], e = c*64 + half*32 + l4*8
  auto load_A = [&](int c, f32x4* xa) {
#pragma unroll
    for (int m = 0; m < 2; ++m) {
      const float* base = (m ? xr1 : xr0) + c * 64 + l4 * 8;
      xa[m * 4 + 0] = *(const f32x4*)(base);
      xa[m * 4 + 1] = *(const f32x4*)(base + 4);
      xa[m * 4 + 2] = *(const f32x4*)(base + 32);
      xa[m * 4 + 3] = *(const f32x4*)(base + 36);
    }
  };
  // B frags: bh[{q0,q1,k0,k1,v0,v1}], bl[{q0,q1,k0,k1}]
  auto load_B = [&](int c, short8* bh, short8* bl) {
    const int e0 = c * 64 + l4 * 8;
    bh[0] = *(const short8*)(bq_h + e0);
    bh[1] = *(const short8*)(bq_h + e0 + 32);
    bh[2] = *(const short8*)(bk_h + e0);
    bh[3] = *(const short8*)(bk_h + e0 + 32);
    bh[4] = *(const short8*)(bv_h + e0);
    bh[5] = *(const short8*)(bv_h + e0 + 32);
    bl[0] = *(const short8*)(bq_l + e0);
    bl[1] = *(const short8*)(bq_l + e0 + 32);
    bl[2] = *(const short8*)(bk_l + e0);
    bl[3] = *(const short8*)(bk_l + e0 + 32);
  };
  // convert + 28 MFMA for one chunk
  auto step = [&](const f32x4* xa, const short8* bh, const short8* bl) {
    short8 ah[4], al[4];   // [m*2+half]
#pragma unroll
    for (int m = 0; m < 2; ++m)
#pragma unroll
      for (int h = 0; h < 2; ++h) {
        short8 hi, lo;
#pragma unroll
        for (int i = 0; i < 4; ++i) {
          const float v = xa[m * 4 + h * 2][i];
          const short hh = f2bf(v);
          hi[i] = hh;
          lo[i] = f2bf(v - bf2f(hh));
        }
#pragma unroll
        for (int i = 0; i < 4; ++i) {
          const float v = xa[m * 4 + h * 2 + 1][i];
          const short hh = f2bf(v);
          hi[4 + i] = hh;
          lo[4 + i] = f2bf(v - bf2f(hh));
        }
        ah[m * 2 + h] = hi;
        al[m * 2 + h] = lo;
      }
#pragma unroll
    for (int m = 0; m < 2; ++m) {
      // q: hi*hi + hi*lo + lo*hi
      acc[m][0] = mfma_16x16x32(ah[m * 2 + 0], bh[0], acc[m][0]);
      acc[m][0] = mfma_16x16x32(ah[m * 2 + 1], bh[1], acc[m][0]);
      acc[m][0] = mfma_16x16x32(ah[m * 2 + 0], bl[0], acc[m][0]);
      acc[m][0] = mfma_16x16x32(ah[m * 2 + 1], bl[1], acc[m][0]);
      acc[m][0] = mfma_16x16x32(al[m * 2 + 0], bh[0], acc[m][0]);
      acc[m][0] = mfma_16x16x32(al[m * 2 + 1], bh[1], acc[m][0]);
      // k
      acc[m][1] = mfma_16x16x32(ah[m * 2 + 0], bh[2], acc[m][1]);
      acc[m][1] = mfma_16x16x32(ah[m * 2 + 1], bh[3], acc[m][1]);
      acc[m][1] = mfma_16x16x32(ah[m * 2 + 0], bl[2], acc[m][1]);
      acc[m][1] = mfma_16x16x32(ah[m * 2 + 1], bl[3], acc[m][1]);
      acc[m][1] = mfma_16x16x32(al[m * 2 + 0], bh[2], acc[m][1]);
      acc[m][1] = mfma_16x16x32(al[m * 2 + 1], bh[3], acc[m][1]);
      // v: hi*hi only (post-softmax tolerance)
      acc[m][2] = mfma_16x16x32(ah[m * 2 + 0], bh[4], acc[m][2]);
      acc[m][2] = mfma_16x16x32(ah[m * 2 + 1], bh[5], acc[m][2]);
    }
  };

  // Double-buffered K-loop, 1.5-chunk lookahead, fully unrolled.
  f32x4 xa0_[8], xa1_[8];
  short8 bh0_[6], bh1_[6], bl0_[4], bl1_[4];
  load_A(0, xa0_);
  load_B(0, bh0_, bl0_);
#pragma unroll
  for (int cc = 0; cc < 8; ++cc) {
    const int c0 = cc * 2, c1 = c0 + 1;
    load_A(c1, xa1_);
    load_B(c1, bh1_, bl1_);
    step(xa0_, bh0_, bl0_);
    if (c1 < 15) {
      load_A(c1 + 1, xa0_);
      load_B(c1 + 1, bh0_, bl0_);
    }
    step(xa1_, bh1_, bl1_);
  }

  // ---- Epilogue: outputs (same layout as v2) ----
  const int hcol = wave * 16 + l15;
#pragma unroll
  for (int jj = 0; jj < 3; ++jj) {
#pragma unroll
    for (int m = 0; m < 2; ++m) {
#pragma unroll
      for (int r = 0; r < 4; ++r) {
        const int trow = row0 + m * 16 + l4 * 4 + r;
        const float val = acc[m][jj][r];
        if (jj == 0) {
          const __hip_bfloat16 hi = __float2bfloat16(val);
          qhi[trow * 64 + hcol] = hi;
          qlo[trow * 64 + hcol] = __float2bfloat16(val - __bfloat162float(hi));
        } else if (jj == 1) {
          const __hip_bfloat16 hi = __float2bfloat16(val);
          khi[trow * 64 + hcol] = hi;
          klo[trow * 64 + hcol] = __float2bfloat16(val - __bfloat162float(hi));
        } else {
          const int bb = trow >> 11, tl = trow & 2047;
          vT[(bb * 64 + hcol) * 2048 + tl] = __float2bfloat16(val);
        }
      }
    }
  }

  // ---- Fused knorm: per-batch max |k_row|^2 (wave w holds k cols w*16+l15) ----
#pragma unroll
  for (int m = 0; m < 2; ++m)
#pragma unroll
    for (int r = 0; r < 4; ++r) {
      float s2 = acc[m][1][r] * acc[m][1][r];
      s2 += __shfl_xor(s2, 1);
      s2 += __shfl_xor(s2, 2);
      s2 += __shfl_xor(s2, 4);
      s2 += __shfl_xor(s2, 8);          // sum over the 16-lane col group
      if (l15 == 0) Ksm[wave][m * 16 + l4 * 4 + r] = s2;
    }
  __syncthreads();
  if (wave == 0) {
    const int row = lane & 31;          // lanes 32-63 duplicate rows 0-31
    float k2 = Ksm[0][row] + Ksm[1][row] + Ksm[2][row] + Ksm[3][row];
#pragma unroll
    for (int off = 1; off < 64; off <<= 1) k2 = fmaxf(k2, __shfl_xor(k2, off));
    if (lane == 0)
      atomicMax((int*)&maxk2[row0 >> 11], __float_as_int(k2));
  }
}

// ---------------------------------------------------------------------------
// Kernel B v11 (unchanged): 32-row wave-tiles + in-wave pipeline + balanced
// strip map; bound-subtract softmax (no shuffles/rescale), MFMA row-sum L,
// plain-sum merge. lb(256,2) only.
// ---------------------------------------------------------------------------
__global__ __launch_bounds__(256, 2) void attn(
    const __hip_bfloat16* __restrict__ qhi, const __hip_bfloat16* __restrict__ qlo,
    const __hip_bfloat16* __restrict__ khi, const __hip_bfloat16* __restrict__ klo,
    const __hip_bfloat16* __restrict__ vT, const float* __restrict__ maxk2,
    float* __restrict__ out) {
  __shared__ __hip_bfloat16 Psm[4][2][16 * 72];  // per-wave, per-m P transpose
  __shared__ float Osm[4][32][65];               // per-wave partial O (fp32)
  __shared__ float Lsm[4][32];                   // per-wave partial L

  const int tid  = threadIdx.x;
  const int wave = tid >> 6;
  const int lane = tid & 63;
  const int l15 = lane & 15, l4 = lane >> 4;

  const int b = blockIdx.x & 7;              // XCD-local batch
  const int g = blockIdx.x >> 3;             // 0..63
  const int ss = (g < 32) ? (63 - g) : (g - 32);  // CU's 2 blocks sum ~const
  const int t0 = ss * 32;
  const int ntiles = (ss >> 1) + 1;          // causal 64-key tiles

  // ---- Q A-frags for 2 m sub-tiles, hi+lo (32 VGPRs) ----
  short8 qh0[2], qh1[2], ql0[2], ql1[2];
#pragma unroll
  for (int m = 0; m < 2; ++m) {
    const __hip_bfloat16* qph = qhi + (b * 2048 + t0 + m * 16 + l15) * 64;
    const __hip_bfloat16* qpl = qlo + (b * 2048 + t0 + m * 16 + l15) * 64;
    qh0[m] = *(const short8*)(qph + l4 * 8);
    qh1[m] = *(const short8*)(qph + 32 + l4 * 8);
    ql0[m] = *(const short8*)(qpl + l4 * 8);
    ql1[m] = *(const short8*)(qpl + 32 + l4 * 8);
  }

  // ---- per-row Cauchy-Schwarz bound c_r = |q_r| * kmax + 2 ----
  const float kmax = sqrtf(maxk2[b]);
  float c_[2][4];
#pragma unroll
  for (int m = 0; m < 2; ++m) {
    float qn = 0.f;
#pragma unroll
    for (int i = 0; i < 8; ++i) {
      const float v0 = bf2f(qh0[m][i]) + bf2f(ql0[m][i]);
      const float v1 = bf2f(qh1[m][i]) + bf2f(ql1[m][i]);
      qn += v0 * v0 + v1 * v1;
    }
    qn += __shfl_xor(qn, 16);
    qn += __shfl_xor(qn, 32);                // |q_{t0+m*16+l15}|^2
    const float crow = sqrtf(qn) * kmax + 2.0f;
#pragma unroll
    for (int r = 0; r < 4; ++r) c_[m][r] = __shfl(crow, l4 * 4 + r);
  }

  short8 ones;                                // bf16 1.0 x8 (B-frag for L)
#pragma unroll
  for (int i = 0; i < 8; ++i) ones[i] = (short)0x3F80;

  f32x4 acc[2][4];
#pragma unroll
  for (int m = 0; m < 2; ++m)
#pragma unroll
    for (int j = 0; j < 4; ++j) acc[m][j] = f32x4{0.f, 0.f, 0.f, 0.f};
  f32x4 accL[2];
  accL[0] = f32x4{0.f, 0.f, 0.f, 0.f};
  accL[1] = f32x4{0.f, 0.f, 0.f, 0.f};

  const __hip_bfloat16* kbase_h = khi + (size_t)b * 2048 * 64;
  const __hip_bfloat16* kbase_l = klo + (size_t)b * 2048 * 64;
  const __hip_bfloat16* vbase   = vT + (size_t)b * 64 * 2048;

  // K frags for the wave's CURRENT tile (reused as prefetch destination)
  short8 kh0[4], kh1[4], kl0[4], kl1[4];
  auto load_K = [&](int k0) {
#pragma unroll
    for (int j = 0; j < 4; ++j) {
      const __hip_bfloat16* kph = kbase_h + (k0 + j * 16 + l15) * 64;
      const __hip_bfloat16* kpl = kbase_l + (k0 + j * 16 + l15) * 64;
      kh0[j] = *(const short8*)(kph + l4 * 8);
      kh1[j] = *(const short8*)(kph + 32 + l4 * 8);
      kl0[j] = *(const short8*)(kpl + l4 * 8);
      kl1[j] = *(const short8*)(kpl + 32 + l4 * 8);
    }
  };

  if (wave < ntiles) load_K(wave << 6);      // prologue prefetch

  for (int kt = wave; kt < ntiles; kt += 4) {
    const int k0 = kt << 6;
    const bool diag = (kt == ntiles - 1);

    // ---- QK + softmax for m=0 (s dies before m=1's lives: caps regs) ----
    f32x4 s_[4];
#pragma unroll
    for (int m = 0; m < 2; ++m) {
      const int rowmax = t0 + m * 16 + 15;
#pragma unroll
      for (int j = 0; j < 4; ++j) {
        if (diag && (k0 + j * 16) > rowmax) {
          s_[j] = f32x4{-1e30f, -1e30f, -1e30f, -1e30f};
        } else {
          f32x4 z = f32x4{0.f, 0.f, 0.f, 0.f};
          z = mfma_16x16x32(qh0[m], kh0[j], z);
          z = mfma_16x16x32(qh1[m], kh1[j], z);
          z = mfma_16x16x32(qh0[m], kl0[j], z);
          z = mfma_16x16x32(qh1[m], kl1[j], z);
          z = mfma_16x16x32(ql0[m], kh0[j], z);
          z = mfma_16x16x32(ql1[m], kh1[j], z);
          s_[j] = z;
        }
      }
      if (m == 1) break;  // m=1: V + prefetch issued before its softmax below
      if (diag) {
#pragma unroll
        for (int j = 0; j < 4; ++j) {
          const int key = k0 + j * 16 + l15;
#pragma unroll
          for (int r = 0; r < 4; ++r)
            if (key > (t0 + l4 * 4 + r)) s_[j][r] = -1e30f;
        }
      }
#pragma unroll
      for (int j = 0; j < 4; ++j)
#pragma unroll
        for (int r = 0; r < 4; ++r) {
          const float pv = __expf(s_[j][r] - c_[0][r]);
          Psm[wave][0][(l4 * 4 + r) * 72 + j * 16 + l15] = __float2bfloat16(pv);
        }
    }

    // ---- V loads for this tile (latency hidden by m=1 softmax + P wait) ----
    short8 vf0[4], vf1[4];
#pragma unroll
    for (int j = 0; j < 4; ++j) {
      const __hip_bfloat16* vp = vbase + (j * 16 + l15) * 2048 + k0;
      vf0[j] = *(const short8*)(vp + l4 * 8);
      vf1[j] = *(const short8*)(vp + 32 + l4 * 8);
    }
    // ---- prefetch next tile's K (K regs free: QK done for both m) ----
    if (kt + 4 < ntiles) load_K((kt + 4) << 6);

    // ---- m=1 softmax (s_ holds m=1 scores) ----
    if (diag) {
#pragma unroll
      for (int j = 0; j < 4; ++j) {
        const int key = k0 + j * 16 + l15;
#pragma unroll
        for (int r = 0; r < 4; ++r)
          if (key > (t0 + 16 + l4 * 4 + r)) s_[j][r] = -1e30f;
      }
    }
#pragma unroll
    for (int j = 0; j < 4; ++j)
#pragma unroll
      for (int r = 0; r < 4; ++r) {
        const float pv = __expf(s_[j][r] - c_[1][r]);
        Psm[wave][1][(l4 * 4 + r) * 72 + j * 16 + l15] = __float2bfloat16(pv);
      }

    WAIT_LGKM0();   // all 32 P writes visible to same wave; vmcnt untouched

    // ---- O += P V ; L += P . 1 ----
#pragma unroll
    for (int m = 0; m < 2; ++m) {
      const short8 pf0 = *(const short8*)&Psm[wave][m][l15 * 72 + l4 * 8];
      const short8 pf1 = *(const short8*)&Psm[wave][m][l15 * 72 + 32 + l4 * 8];
#pragma unroll
      for (int j = 0; j < 4; ++j) {
        acc[m][j] = mfma_16x16x32(pf0, vf0[j], acc[m][j]);
        acc[m][j] = mfma_16x16x32(pf1, vf1[j], acc[m][j]);
      }
      accL[m] = mfma_16x16x32(pf0, ones, accL[m]);
      accL[m] = mfma_16x16x32(pf1, ones, accL[m]);
    }
  }

  // ---- per-wave partials into LDS (fp32, plain sums) ----
#pragma unroll
  for (int m = 0; m < 2; ++m) {
#pragma unroll
    for (int j = 0; j < 4; ++j)
#pragma unroll
      for (int r = 0; r < 4; ++r)
        Osm[wave][m * 16 + l4 * 4 + r][j * 16 + l15] = acc[m][j][r];
    if (l15 == 0) {
#pragma unroll
      for (int r = 0; r < 4; ++r)
        Lsm[wave][m * 16 + l4 * 4 + r] = accL[m][r];
    }
  }
  __syncthreads();

  // ---- cross-wave merge: PLAIN SUM (c_r uniform per row -> exact) ----
#pragma unroll
  for (int rr = 0; rr < 8; ++rr) {
    const int row = wave * 8 + rr;
    const float L = Lsm[0][row] + Lsm[1][row] + Lsm[2][row] + Lsm[3][row];
    const float O = Osm[0][row][lane] + Osm[1][row][lane] +
                    Osm[2][row][lane] + Osm[3][row][lane];
    out[(b * 2048 + t0 + row) * 64 + lane] = O / L;
  }
}

// ---------------------------------------------------------------------------
extern "C" void kernel_launch(void* const* d_in, const int* in_sizes, int n_in,
                              void* d_out, int out_size, void* d_ws, size_t ws_size,
                              hipStream_t stream) {
  const float* x  = (const float*)d_in[0];
  const float* Wq = (const float*)d_in[1];
  const float* Wk = (const float*)d_in[2];
  const float* Wv = (const float*)d_in[3];
  float* out = (float*)d_out;

  char* ws = (char*)d_ws;
  __hip_bfloat16* Wthi = (__hip_bfloat16*)ws;                   // 384 KB
  __hip_bfloat16* Wtlo = (__hip_bfloat16*)(ws + 393216);        // 384 KB
  __hip_bfloat16* qhi  = (__hip_bfloat16*)(ws + 786432);        // 2 MB each
  __hip_bfloat16* qlo  = (__hip_bfloat16*)(ws + 786432 + 1 * 2097152);
  __hip_bfloat16* khi  = (__hip_bfloat16*)(ws + 786432 + 2 * 2097152);
  __hip_bfloat16* klo  = (__hip_bfloat16*)(ws + 786432 + 3 * 2097152);
  __hip_bfloat16* vT   = (__hip_bfloat16*)(ws + 786432 + 4 * 2097152);
  float* maxk2         = (float*)(ws + 786432 + 5 * 2097152);   // 32 B

  prep_w<<<192, 256, 0, stream>>>(Wq, Wk, Wv, Wthi, Wtlo, maxk2);
  qkv_gemm<<<512, 256, 0, stream>>>(x, Wthi, Wtlo, qhi, qlo, khi, klo, vT, maxk2);
  attn<<<512, 256, 0, stream>>>(qhi, qlo, khi, klo, vT, maxk2, out);
}

// Round 9
// 184.092 us; speedup vs baseline: 1.0091x; 1.0091x over previous
//
#include <hip/hip_runtime.h>
#include <hip/hip_bf16.h>

// Problem constants
#define BB 8
#define TT 2048
#define EE 1024
#define HH 64

typedef __attribute__((ext_vector_type(8))) short short8;
typedef __attribute__((ext_vector_type(4))) float f32x4;

__device__ inline f32x4 mfma_16x16x32(short8 a, short8 b, f32x4 c) {
  return __builtin_amdgcn_mfma_f32_16x16x32_bf16(a, b, c, 0, 0, 0);
}

__device__ inline short f2bf(float f) {
  __hip_bfloat16 h = __float2bfloat16(f);
  return *reinterpret_cast<short*>(&h);
}
__device__ inline float bf2f(short s) {
  __hip_bfloat16 h = *reinterpret_cast<__hip_bfloat16*>(&s);
  return __bfloat162float(h);
}

// wait lgkmcnt(0) only; leave vmcnt/expcnt unconstrained
#define WAIT_LGKM0() __builtin_amdgcn_s_waitcnt(0xC07F)
// full scheduling fence: nothing may be reordered across this point
#define SCHED_FENCE() __builtin_amdgcn_sched_barrier(0)

// ---------------------------------------------------------------------------
// Kernel 0: split-precision transposed weights. Block 0 also zeroes maxk2.
// ---------------------------------------------------------------------------
__global__ void prep_w(const float* __restrict__ Wq, const float* __restrict__ Wk,
                       const float* __restrict__ Wv,
                       __hip_bfloat16* __restrict__ Wthi,
                       __hip_bfloat16* __restrict__ Wtlo,
                       float* __restrict__ maxk2) {
  const int n = blockIdx.x;          // 0..191
  if (n == 0 && threadIdx.x < 8) maxk2[threadIdx.x] = 0.f;
  const int m = n >> 6;
  const int h = n & 63;
  const float* W = (m == 0) ? Wq : (m == 1) ? Wk : Wv;
  const int e0 = threadIdx.x * 4;    // 256 threads * 4 = 1024
#pragma unroll
  for (int j = 0; j < 4; ++j) {
    const float w = W[(e0 + j) * 64 + h];
    const __hip_bfloat16 hi = __float2bfloat16(w);
    Wthi[n * 1024 + e0 + j] = hi;
    Wtlo[n * 1024 + e0 + j] = __float2bfloat16(w - __bfloat162float(hi));
  }
}

// ---------------------------------------------------------------------------
// Kernel A v4: v3's barrier-free register-direct GEMM + SCHED FENCES.
// v3 post-mortem (77us): compiler allocated only 64 VGPR and SANK all loads
// to their use points -> pipeline destroyed, ~600GB/s latency-bound HBM.
// Fix: __builtin_amdgcn_sched_barrier(0) between next-chunk load ISSUE and
// current-chunk step() -> loads must issue early and stay live across the
// compute body (forces ~160 VGPR materialization, waits land one body late).
// Tripwire: VGPR_Count must be >=150; WRITE_SIZE ~10MB (no spill).
// Fused knorm epilogue unchanged (deletes knorm launch).
// ---------------------------------------------------------------------------
__global__ __launch_bounds__(256, 2) void qkv_gemm(
    const float* __restrict__ x,
    const __hip_bfloat16* __restrict__ Wthi, const __hip_bfloat16* __restrict__ Wtlo,
    __hip_bfloat16* __restrict__ qhi, __hip_bfloat16* __restrict__ qlo,
    __hip_bfloat16* __restrict__ khi, __hip_bfloat16* __restrict__ klo,
    __hip_bfloat16* __restrict__ vT, float* __restrict__ maxk2) {
  __shared__ float Ksm[4][32];

  const int tid  = threadIdx.x;
  const int wave = tid >> 6;
  const int lane = tid & 63;
  const int l15 = lane & 15, l4 = lane >> 4;
  const int row0 = blockIdx.x * 32;

  // Wave w owns output col-groups j = {w, w+4, w+8} (q, k, v stripes).
  const __hip_bfloat16* bq_h = Wthi + ((wave)     * 16 + l15) * 1024;
  const __hip_bfloat16* bk_h = Wthi + ((wave + 4) * 16 + l15) * 1024;
  const __hip_bfloat16* bv_h = Wthi + ((wave + 8) * 16 + l15) * 1024;
  const __hip_bfloat16* bq_l = Wtlo + ((wave)     * 16 + l15) * 1024;
  const __hip_bfloat16* bk_l = Wtlo + ((wave + 4) * 16 + l15) * 1024;
  const float* xr0 = x + (size_t)(row0 + l15) * 1024;       // m=0 rows
  const float* xr1 = x + (size_t)(row0 + 16 + l15) * 1024;  // m=1 rows

  f32x4 acc[2][3];
#pragma unroll
  for (int m = 0; m < 2; ++m)
#pragma unroll
    for (int j = 0; j < 3; ++j) acc[m][j] = f32x4{0.f, 0.f, 0.f, 0.f};

  // A fp32 loads: xa[m*4 + half*2 + {0,1}], e = c*64 + half*32 + l4*8
  auto load_A = [&](int c, f32x4* xa) {
#pragma unroll
    for (int m = 0; m < 2; ++m) {
      const float* base = (m ? xr1 : xr0) + c * 64 + l4 * 8;
      xa[m * 4 + 0] = *(const f32x4*)(base);
      xa[m * 4 + 1] = *(const f32x4*)(base + 4);
      xa[m * 4 + 2] = *(const f32x4*)(base + 32);
      xa[m * 4 + 3] = *(const f32x4*)(base + 36);
    }
  };
  // B frags: bh[{q0,q1,k0,k1,v0,v1}], bl[{q0,q1,k0,k1}]
  auto load_B = [&](int c, short8* bh, short8* bl) {
    const int e0 = c * 64 + l4 * 8;
    bh[0] = *(const short8*)(bq_h + e0);
    bh[1] = *(const short8*)(bq_h + e0 + 32);
    bh[2] = *(const short8*)(bk_h + e0);
    bh[3] = *(const short8*)(bk_h + e0 + 32);
    bh[4] = *(const short8*)(bv_h + e0);
    bh[5] = *(const short8*)(bv_h + e0 + 32);
    bl[0] = *(const short8*)(bq_l + e0);
    bl[1] = *(const short8*)(bq_l + e0 + 32);
    bl[2] = *(const short8*)(bk_l + e0);
    bl[3] = *(const short8*)(bk_l + e0 + 32);
  };
  // convert + 28 MFMA for one chunk
  auto step = [&](const f32x4* xa, const short8* bh, const short8* bl) {
    short8 ah[4], al[4];   // [m*2+half]
#pragma unroll
    for (int m = 0; m < 2; ++m)
#pragma unroll
      for (int h = 0; h < 2; ++h) {
        short8 hi, lo;
#pragma unroll
        for (int i = 0; i < 4; ++i) {
          const float v = xa[m * 4 + h * 2][i];
          const short hh = f2bf(v);
          hi[i] = hh;
          lo[i] = f2bf(v - bf2f(hh));
        }
#pragma unroll
        for (int i = 0; i < 4; ++i) {
          const float v = xa[m * 4 + h * 2 + 1][i];
          const short hh = f2bf(v);
          hi[4 + i] = hh;
          lo[4 + i] = f2bf(v - bf2f(hh));
        }
        ah[m * 2 + h] = hi;
        al[m * 2 + h] = lo;
      }
#pragma unroll
    for (int m = 0; m < 2; ++m) {
      // q: hi*hi + hi*lo + lo*hi
      acc[m][0] = mfma_16x16x32(ah[m * 2 + 0], bh[0], acc[m][0]);
      acc[m][0] = mfma_16x16x32(ah[m * 2 + 1], bh[1], acc[m][0]);
      acc[m][0] = mfma_16x16x32(ah[m * 2 + 0], bl[0], acc[m][0]);
      acc[m][0] = mfma_16x16x32(ah[m * 2 + 1], bl[1], acc[m][0]);
      acc[m][0] = mfma_16x16x32(al[m * 2 + 0], bh[0], acc[m][0]);
      acc[m][0] = mfma_16x16x32(al[m * 2 + 1], bh[1], acc[m][0]);
      // k
      acc[m][1] = mfma_16x16x32(ah[m * 2 + 0], bh[2], acc[m][1]);
      acc[m][1] = mfma_16x16x32(ah[m * 2 + 1], bh[3], acc[m][1]);
      acc[m][1] = mfma_16x16x32(ah[m * 2 + 0], bl[2], acc[m][1]);
      acc[m][1] = mfma_16x16x32(ah[m * 2 + 1], bl[3], acc[m][1]);
      acc[m][1] = mfma_16x16x32(al[m * 2 + 0], bh[2], acc[m][1]);
      acc[m][1] = mfma_16x16x32(al[m * 2 + 1], bh[3], acc[m][1]);
      // v: hi*hi only (post-softmax tolerance)
      acc[m][2] = mfma_16x16x32(ah[m * 2 + 0], bh[4], acc[m][2]);
      acc[m][2] = mfma_16x16x32(ah[m * 2 + 1], bh[5], acc[m][2]);
    }
  };

  // Double-buffered K-loop, 1.5-chunk lookahead, schedule-fenced.
  f32x4 xa0_[8], xa1_[8];
  short8 bh0_[6], bh1_[6], bl0_[4], bl1_[4];
  load_A(0, xa0_);
  load_B(0, bh0_, bl0_);
  SCHED_FENCE();
#pragma unroll
  for (int cc = 0; cc < 8; ++cc) {
    const int c0 = cc * 2, c1 = c0 + 1;
    load_A(c1, xa1_);
    load_B(c1, bh1_, bl1_);
    SCHED_FENCE();          // loads(c1) must ISSUE before step(c0) executes
    step(xa0_, bh0_, bl0_);
    SCHED_FENCE();
    if (c1 < 15) {
      load_A(c1 + 1, xa0_);
      load_B(c1 + 1, bh0_, bl0_);
    }
    SCHED_FENCE();          // loads(c1+1) issue before step(c1)
    step(xa1_, bh1_, bl1_);
    SCHED_FENCE();
  }

  // ---- Epilogue: outputs (same layout as v2/v3) ----
  const int hcol = wave * 16 + l15;
#pragma unroll
  for (int jj = 0; jj < 3; ++jj) {
#pragma unroll
    for (int m = 0; m < 2; ++m) {
#pragma unroll
      for (int r = 0; r < 4; ++r) {
        const int trow = row0 + m * 16 + l4 * 4 + r;
        const float val = acc[m][jj][r];
        if (jj == 0) {
          const __hip_bfloat16 hi = __float2bfloat16(val);
          qhi[trow * 64 + hcol] = hi;
          qlo[trow * 64 + hcol] = __float2bfloat16(val - __bfloat162float(hi));
        } else if (jj == 1) {
          const __hip_bfloat16 hi = __float2bfloat16(val);
          khi[trow * 64 + hcol] = hi;
          klo[trow * 64 + hcol] = __float2bfloat16(val - __bfloat162float(hi));
        } else {
          const int bb = trow >> 11, tl = trow & 2047;
          vT[(bb * 64 + hcol) * 2048 + tl] = __float2bfloat16(val);
        }
      }
    }
  }

  // ---- Fused knorm: per-batch max |k_row|^2 (wave w holds k cols w*16+l15) ----
#pragma unroll
  for (int m = 0; m < 2; ++m)
#pragma unroll
    for (int r = 0; r < 4; ++r) {
      float s2 = acc[m][1][r] * acc[m][1][r];
      s2 += __shfl_xor(s2, 1);
      s2 += __shfl_xor(s2, 2);
      s2 += __shfl_xor(s2, 4);
      s2 += __shfl_xor(s2, 8);          // sum over the 16-lane col group
      if (l15 == 0) Ksm[wave][m * 16 + l4 * 4 + r] = s2;
    }
  __syncthreads();
  if (wave == 0) {
    const int row = lane & 31;          // lanes 32-63 duplicate rows 0-31
    float k2 = Ksm[0][row] + Ksm[1][row] + Ksm[2][row] + Ksm[3][row];
#pragma unroll
    for (int off = 1; off < 64; off <<= 1) k2 = fmaxf(k2, __shfl_xor(k2, off));
    if (lane == 0)
      atomicMax((int*)&maxk2[row0 >> 11], __float_as_int(k2));
  }
}

// ---------------------------------------------------------------------------
// Kernel B v11 (unchanged): 32-row wave-tiles + in-wave pipeline + balanced
// strip map; bound-subtract softmax (no shuffles/rescale), MFMA row-sum L,
// plain-sum merge. lb(256,2) only.
// ---------------------------------------------------------------------------
__global__ __launch_bounds__(256, 2) void attn(
    const __hip_bfloat16* __restrict__ qhi, const __hip_bfloat16* __restrict__ qlo,
    const __hip_bfloat16* __restrict__ khi, const __hip_bfloat16* __restrict__ klo,
    const __hip_bfloat16* __restrict__ vT, const float* __restrict__ maxk2,
    float* __restrict__ out) {
  __shared__ __hip_bfloat16 Psm[4][2][16 * 72];  // per-wave, per-m P transpose
  __shared__ float Osm[4][32][65];               // per-wave partial O (fp32)
  __shared__ float Lsm[4][32];                   // per-wave partial L

  const int tid  = threadIdx.x;
  const int wave = tid >> 6;
  const int lane = tid & 63;
  const int l15 = lane & 15, l4 = lane >> 4;

  const int b = blockIdx.x & 7;              // XCD-local batch
  const int g = blockIdx.x >> 3;             // 0..63
  const int ss = (g < 32) ? (63 - g) : (g - 32);  // CU's 2 blocks sum ~const
  const int t0 = ss * 32;
  const int ntiles = (ss >> 1) + 1;          // causal 64-key tiles

  // ---- Q A-frags for 2 m sub-tiles, hi+lo (32 VGPRs) ----
  short8 qh0[2], qh1[2], ql0[2], ql1[2];
#pragma unroll
  for (int m = 0; m < 2; ++m) {
    const __hip_bfloat16* qph = qhi + (b * 2048 + t0 + m * 16 + l15) * 64;
    const __hip_bfloat16* qpl = qlo + (b * 2048 + t0 + m * 16 + l15) * 64;
    qh0[m] = *(const short8*)(qph + l4 * 8);
    qh1[m] = *(const short8*)(qph + 32 + l4 * 8);
    ql0[m] = *(const short8*)(qpl + l4 * 8);
    ql1[m] = *(const short8*)(qpl + 32 + l4 * 8);
  }

  // ---- per-row Cauchy-Schwarz bound c_r = |q_r| * kmax + 2 ----
  const float kmax = sqrtf(maxk2[b]);
  float c_[2][4];
#pragma unroll
  for (int m = 0; m < 2; ++m) {
    float qn = 0.f;
#pragma unroll
    for (int i = 0; i < 8; ++i) {
      const float v0 = bf2f(qh0[m][i]) + bf2f(ql0[m][i]);
      const float v1 = bf2f(qh1[m][i]) + bf2f(ql1[m][i]);
      qn += v0 * v0 + v1 * v1;
    }
    qn += __shfl_xor(qn, 16);
    qn += __shfl_xor(qn, 32);                // |q_{t0+m*16+l15}|^2
    const float crow = sqrtf(qn) * kmax + 2.0f;
#pragma unroll
    for (int r = 0; r < 4; ++r) c_[m][r] = __shfl(crow, l4 * 4 + r);
  }

  short8 ones;                                // bf16 1.0 x8 (B-frag for L)
#pragma unroll
  for (int i = 0; i < 8; ++i) ones[i] = (short)0x3F80;

  f32x4 acc[2][4];
#pragma unroll
  for (int m = 0; m < 2; ++m)
#pragma unroll
    for (int j = 0; j < 4; ++j) acc[m][j] = f32x4{0.f, 0.f, 0.f, 0.f};
  f32x4 accL[2];
  accL[0] = f32x4{0.f, 0.f, 0.f, 0.f};
  accL[1] = f32x4{0.f, 0.f, 0.f, 0.f};

  const __hip_bfloat16* kbase_h = khi + (size_t)b * 2048 * 64;
  const __hip_bfloat16* kbase_l = klo + (size_t)b * 2048 * 64;
  const __hip_bfloat16* vbase   = vT + (size_t)b * 64 * 2048;

  // K frags for the wave's CURRENT tile (reused as prefetch destination)
  short8 kh0[4], kh1[4], kl0[4], kl1[4];
  auto load_K = [&](int k0) {
#pragma unroll
    for (int j = 0; j < 4; ++j) {
      const __hip_bfloat16* kph = kbase_h + (k0 + j * 16 + l15) * 64;
      const __hip_bfloat16* kpl = kbase_l + (k0 + j * 16 + l15) * 64;
      kh0[j] = *(const short8*)(kph + l4 * 8);
      kh1[j] = *(const short8*)(kph + 32 + l4 * 8);
      kl0[j] = *(const short8*)(kpl + l4 * 8);
      kl1[j] = *(const short8*)(kpl + 32 + l4 * 8);
    }
  };

  if (wave < ntiles) load_K(wave << 6);      // prologue prefetch

  for (int kt = wave; kt < ntiles; kt += 4) {
    const int k0 = kt << 6;
    const bool diag = (kt == ntiles - 1);

    // ---- QK + softmax for m=0 (s dies before m=1's lives: caps regs) ----
    f32x4 s_[4];
#pragma unroll
    for (int m = 0; m < 2; ++m) {
      const int rowmax = t0 + m * 16 + 15;
#pragma unroll
      for (int j = 0; j < 4; ++j) {
        if (diag && (k0 + j * 16) > rowmax) {
          s_[j] = f32x4{-1e30f, -1e30f, -1e30f, -1e30f};
        } else {
          f32x4 z = f32x4{0.f, 0.f, 0.f, 0.f};
          z = mfma_16x16x32(qh0[m], kh0[j], z);
          z = mfma_16x16x32(qh1[m], kh1[j], z);
          z = mfma_16x16x32(qh0[m], kl0[j], z);
          z = mfma_16x16x32(qh1[m], kl1[j], z);
          z = mfma_16x16x32(ql0[m], kh0[j], z);
          z = mfma_16x16x32(ql1[m], kh1[j], z);
          s_[j] = z;
        }
      }
      if (m == 1) break;  // m=1: V + prefetch issued before its softmax below
      if (diag) {
#pragma unroll
        for (int j = 0; j < 4; ++j) {
          const int key = k0 + j * 16 + l15;
#pragma unroll
          for (int r = 0; r < 4; ++r)
            if (key > (t0 + l4 * 4 + r)) s_[j][r] = -1e30f;
        }
      }
#pragma unroll
      for (int j = 0; j < 4; ++j)
#pragma unroll
        for (int r = 0; r < 4; ++r) {
          const float pv = __expf(s_[j][r] - c_[0][r]);
          Psm[wave][0][(l4 * 4 + r) * 72 + j * 16 + l15] = __float2bfloat16(pv);
        }
    }

    // ---- V loads for this tile (latency hidden by m=1 softmax + P wait) ----
    short8 vf0[4], vf1[4];
#pragma unroll
    for (int j = 0; j < 4; ++j) {
      const __hip_bfloat16* vp = vbase + (j * 16 + l15) * 2048 + k0;
      vf0[j] = *(const short8*)(vp + l4 * 8);
      vf1[j] = *(const short8*)(vp + 32 + l4 * 8);
    }
    // ---- prefetch next tile's K (K regs free: QK done for both m) ----
    if (kt + 4 < ntiles) load_K((kt + 4) << 6);

    // ---- m=1 softmax (s_ holds m=1 scores) ----
    if (diag) {
#pragma unroll
      for (int j = 0; j < 4; ++j) {
        const int key = k0 + j * 16 + l15;
#pragma unroll
        for (int r = 0; r < 4; ++r)
          if (key > (t0 + 16 + l4 * 4 + r)) s_[j][r] = -1e30f;
      }
    }
#pragma unroll
    for (int j = 0; j < 4; ++j)
#pragma unroll
      for (int r = 0; r < 4; ++r) {
        const float pv = __expf(s_[j][r] - c_[1][r]);
        Psm[wave][1][(l4 * 4 + r) * 72 + j * 16 + l15] = __float2bfloat16(pv);
      }

    WAIT_LGKM0();   // all 32 P writes visible to same wave; vmcnt untouched

    // ---- O += P V ; L += P . 1 ----
#pragma unroll
    for (int m = 0; m < 2; ++m) {
      const short8 pf0 = *(const short8*)&Psm[wave][m][l15 * 72 + l4 * 8];
      const short8 pf1 = *(const short8*)&Psm[wave][m][l15 * 72 + 32 + l4 * 8];
#pragma unroll
      for (int j = 0; j < 4; ++j) {
        acc[m][j] = mfma_16x16x32(pf0, vf0[j], acc[m][j]);
        acc[m][j] = mfma_16x16x32(pf1, vf1[j], acc[m][j]);
      }
      accL[m] = mfma_16x16x32(pf0, ones, accL[m]);
      accL[m] = mfma_16x16x32(pf1, ones, accL[m]);
    }
  }

  // ---- per-wave partials into LDS (fp32, plain sums) ----
#pragma unroll
  for (int m = 0; m < 2; ++m) {
#pragma unroll
    for (int j = 0; j < 4; ++j)
#pragma unroll
      for (int r = 0; r < 4; ++r)
        Osm[wave][m * 16 + l4 * 4 + r][j * 16 + l15] = acc[m][j][r];
    if (l15 == 0) {
#pragma unroll
      for (int r = 0; r < 4; ++r)
        Lsm[wave][m * 16 + l4 * 4 + r] = accL[m][r];
    }
  }
  __syncthreads();

  // ---- cross-wave merge: PLAIN SUM (c_r uniform per row -> exact) ----
#pragma unroll
  for (int rr = 0; rr < 8; ++rr) {
    const int row = wave * 8 + rr;
    const float L = Lsm[0][row] + Lsm[1][row] + Lsm[2][row] + Lsm[3][row];
    const float O = Osm[0][row][lane] + Osm[1][row][lane] +
                    Osm[2][row][lane] + Osm[3][row][lane];
    out[(b * 2048 + t0 + row) * 64 + lane] = O / L;
  }
}

// ---------------------------------------------------------------------------
extern "C" void kernel_launch(void* const* d_in, const int* in_sizes, int n_in,
                              void* d_out, int out_size, void* d_ws, size_t ws_size,
                              hipStream_t stream) {
  const float* x  = (const float*)d_in[0];
  const float* Wq = (const float*)d_in[1];
  const float* Wk = (const float*)d_in[2];
  const float* Wv = (const float*)d_in[3];
  float* out = (float*)d_out;

  char* ws = (char*)d_ws;
  __hip_bfloat16* Wthi = (__hip_bfloat16*)ws;                   // 384 KB
  __hip_bfloat16* Wtlo = (__hip_bfloat16*)(ws + 393216);        // 384 KB
  __hip_bfloat16* qhi  = (__hip_bfloat16*)(ws + 786432);        // 2 MB each
  __hip_bfloat16* qlo  = (__hip_bfloat16*)(ws + 786432 + 1 * 2097152);
  __hip_bfloat16* khi  = (__hip_bfloat16*)(ws + 786432 + 2 * 2097152);
  __hip_bfloat16* klo  = (__hip_bfloat16*)(ws + 786432 + 3 * 2097152);
  __hip_bfloat16* vT   = (__hip_bfloat16*)(ws + 786432 + 4 * 2097152);
  float* maxk2         = (float*)(ws + 786432 + 5 * 2097152);   // 32 B

  prep_w<<<192, 256, 0, stream>>>(Wq, Wk, Wv, Wthi, Wtlo, maxk2);
  qkv_gemm<<<512, 256, 0, stream>>>(x, Wthi, Wtlo, qhi, qlo, khi, klo, vT, maxk2);
  attn<<<512, 256, 0, stream>>>(qhi, qlo, khi, klo, vT, maxk2, out);
}

// Round 11
// 149.487 us; speedup vs baseline: 1.2427x; 1.2315x over previous
//
#include <hip/hip_runtime.h>
#include <hip/hip_bf16.h>

// Problem constants
#define BB 8
#define TT 2048
#define EE 1024
#define HH 64

typedef __attribute__((ext_vector_type(8))) short short8;
typedef __attribute__((ext_vector_type(4))) float f32x4;

__device__ inline f32x4 mfma_16x16x32(short8 a, short8 b, f32x4 c) {
  return __builtin_amdgcn_mfma_f32_16x16x32_bf16(a, b, c, 0, 0, 0);
}

// async global->LDS, 16B per lane, LDS dest = wave-uniform base + lane*16
__device__ inline void gload_lds16(const __hip_bfloat16* g, __hip_bfloat16* l) {
  __builtin_amdgcn_global_load_lds((const __attribute__((address_space(1))) void*)g,
                                   (__attribute__((address_space(3))) void*)l,
                                   16, 0, 0);
}

__device__ inline short f2bf(float f) {
  __hip_bfloat16 h = __float2bfloat16(f);
  return *reinterpret_cast<short*>(&h);
}
__device__ inline float bf2f(short s) {
  __hip_bfloat16 h = *reinterpret_cast<__hip_bfloat16*>(&s);
  return __bfloat162float(h);
}

// wait lgkmcnt(0) only; leave vmcnt/expcnt unconstrained
#define WAIT_LGKM0() __builtin_amdgcn_s_waitcnt(0xC07F)
#define SCHED_FENCE() __builtin_amdgcn_sched_barrier(0)
// counted waits (inline asm: compiler must not widen them to vmcnt(0))
#define ASM_WAIT_VM4()  asm volatile("s_waitcnt vmcnt(4)" ::: "memory")
#define ASM_WAIT_VM0()  asm volatile("s_waitcnt vmcnt(0)" ::: "memory")
#define ASM_WAIT_LGKM() asm volatile("s_waitcnt lgkmcnt(0)" ::: "memory")

// ---------------------------------------------------------------------------
// Kernel 0: split-precision transposed weights. Block 0 also zeroes maxk2.
// ---------------------------------------------------------------------------
__global__ void prep_w(const float* __restrict__ Wq, const float* __restrict__ Wk,
                       const float* __restrict__ Wv,
                       __hip_bfloat16* __restrict__ Wthi,
                       __hip_bfloat16* __restrict__ Wtlo,
                       float* __restrict__ maxk2) {
  const int n = blockIdx.x;          // 0..191
  if (n == 0 && threadIdx.x < 8) maxk2[threadIdx.x] = 0.f;
  const int m = n >> 6;
  const int h = n & 63;
  const float* W = (m == 0) ? Wq : (m == 1) ? Wk : Wv;
  const int e0 = threadIdx.x * 4;    // 256 threads * 4 = 1024
#pragma unroll
  for (int j = 0; j < 4; ++j) {
    const float w = W[(e0 + j) * 64 + h];
    const __hip_bfloat16 hi = __float2bfloat16(w);
    Wthi[n * 1024 + e0 + j] = hi;
    Wtlo[n * 1024 + e0 + j] = __float2bfloat16(w - __bfloat162float(hi));
  }
}

// ---------------------------------------------------------------------------
// Kernel A v5: v1's 64-row LDS-staged GEMM (best measured: 43us) + T4
// counted vmcnt across a RAW s_barrier. v1's stall: __syncthreads' vmcnt(0)
// drained the x prefetch queue every chunk. Now: x prefetched TWO chunks
// ahead (2 reg slots); per chunk issue {B(c+1) gload_lds, x(c+2)};
// s_waitcnt vmcnt(4) drains B(c+1)+x(c+1) but KEEPS x(c+2) in flight
// across the raw barrier; lgkmcnt(0) covers write_A. Fully unrolled so
// wait immediates are static. sched_barrier(0) after each asm wait
// (rule 18). Edge c=14 uses VM0 (no x(16): VM4 would leave B(15) live).
// Fused knorm epilogue (verified r8/r9) on k-acc.
// ---------------------------------------------------------------------------
__global__ __launch_bounds__(256) void qkv_gemm(
    const float* __restrict__ x,
    const __hip_bfloat16* __restrict__ Wthi, const __hip_bfloat16* __restrict__ Wtlo,
    __hip_bfloat16* __restrict__ qhi, __hip_bfloat16* __restrict__ qlo,
    __hip_bfloat16* __restrict__ khi, __hip_bfloat16* __restrict__ klo,
    __hip_bfloat16* __restrict__ vT, float* __restrict__ maxk2) {
  __shared__ __hip_bfloat16 Ahi[2][64 * 72];
  __shared__ __hip_bfloat16 Alo[2][64 * 72];
  __shared__ __hip_bfloat16 Bhi[2][192 * 64];
  __shared__ __hip_bfloat16 Blo[2][128 * 64];
  __shared__ float Ksm[4][16];

  const int tid  = threadIdx.x;
  const int wave = tid >> 6;
  const int lane = tid & 63;
  const int row0 = blockIdx.x * 64;

  const int lr = tid >> 2;           // 0..63 (row in strip)
  const int le = (tid & 3) * 16;     // 0..48 (col, floats)
  const float* xrow = x + (row0 + lr) * 1024 + le;

  f32x4 acc[12];
#pragma unroll
  for (int j = 0; j < 12; ++j) acc[j] = f32x4{0.f, 0.f, 0.f, 0.f};

  const int l15 = lane & 15, l4 = lane >> 4;

  auto issue_B = [&](int c, int buf) {
    const int g = (lane & 7) ^ ((lane >> 3) & 7);
#pragma unroll
    for (int s = 0; s < 6; ++s) {
      const int qq = wave * 6 + s;
      const int n  = qq * 8 + (lane >> 3);
      gload_lds16(Wthi + n * 1024 + c * 64 + g * 8, &Bhi[buf][qq * 512]);
      if (qq < 16)
        gload_lds16(Wtlo + n * 1024 + c * 64 + g * 8, &Blo[buf][qq * 512]);
    }
  };
  auto write_A = [&](int buf, const f32x4* xr) {
    short8 h0, h1, l0, l1;
    const float* xf = (const float*)xr;
#pragma unroll
    for (int j = 0; j < 8; ++j) {
      const float v = xf[j];
      const short h = f2bf(v);
      h0[j] = h;
      l0[j] = f2bf(v - bf2f(h));
    }
#pragma unroll
    for (int j = 0; j < 8; ++j) {
      const float v = xf[8 + j];
      const short h = f2bf(v);
      h1[j] = h;
      l1[j] = f2bf(v - bf2f(h));
    }
    *(short8*)&Ahi[buf][lr * 72 + le]     = h0;
    *(short8*)&Ahi[buf][lr * 72 + le + 8] = h1;
    *(short8*)&Alo[buf][lr * 72 + le]     = l0;
    *(short8*)&Alo[buf][lr * 72 + le + 8] = l1;
  };
  auto compute = [&](int buf) {
    const int tr = wave * 16 + l15;
    short8 ah0 = *(const short8*)&Ahi[buf][tr * 72 + l4 * 8];
    short8 ah1 = *(const short8*)&Ahi[buf][tr * 72 + 32 + l4 * 8];
    short8 al0 = *(const short8*)&Alo[buf][tr * 72 + l4 * 8];
    short8 al1 = *(const short8*)&Alo[buf][tr * 72 + 32 + l4 * 8];
#pragma unroll
    for (int j = 0; j < 12; ++j) {
      const int n  = j * 16 + l15;
      const int o0 = ((l4)     ^ (n & 7)) * 8;
      const int o1 = ((4 + l4) ^ (n & 7)) * 8;
      short8 bh0 = *(const short8*)&Bhi[buf][n * 64 + o0];
      short8 bh1 = *(const short8*)&Bhi[buf][n * 64 + o1];
      acc[j] = mfma_16x16x32(ah0, bh0, acc[j]);
      acc[j] = mfma_16x16x32(ah1, bh1, acc[j]);
      if (j < 8) {
        short8 bl0 = *(const short8*)&Blo[buf][n * 64 + o0];
        short8 bl1 = *(const short8*)&Blo[buf][n * 64 + o1];
        acc[j] = mfma_16x16x32(ah0, bl0, acc[j]);
        acc[j] = mfma_16x16x32(ah1, bl1, acc[j]);
        acc[j] = mfma_16x16x32(al0, bh0, acc[j]);
        acc[j] = mfma_16x16x32(al1, bh1, acc[j]);
      }
    }
  };

  // ---- Prologue: x(0)->xs0, B(0), x(1)->xs1; drain all but x(1) ----
  f32x4 xs0[4], xs1[4];
  {
    const f32x4* p = (const f32x4*)xrow;
    xs0[0] = p[0]; xs0[1] = p[1]; xs0[2] = p[2]; xs0[3] = p[3];
  }
  issue_B(0, 0);
  {
    const f32x4* p = (const f32x4*)(xrow + 64);
    xs1[0] = p[0]; xs1[1] = p[1]; xs1[2] = p[2]; xs1[3] = p[3];
  }
  ASM_WAIT_VM4();          // B(0)+x(0) done; x(1) stays in flight
  SCHED_FENCE();
  write_A(0, xs0);
  ASM_WAIT_LGKM();
  SCHED_FENCE();
  __builtin_amdgcn_s_barrier();
  SCHED_FENCE();

#pragma unroll
  for (int c = 0; c < 16; ++c) {
    const int p = c & 1;
    if (c < 15) issue_B(c + 1, p ^ 1);
    if (c < 14) {          // x(c+2) into slot[c&1] (its old contents consumed)
      const f32x4* pp = (const f32x4*)(xrow + (c + 2) * 64);
      f32x4* dst = (p == 0) ? xs0 : xs1;
      dst[0] = pp[0]; dst[1] = pp[1]; dst[2] = pp[2]; dst[3] = pp[3];
    }
    compute(p);
    if (c < 15) {
      if (c < 14) { ASM_WAIT_VM4(); }   // drain B(c+1)+x(c+1); keep x(c+2)
      else        { ASM_WAIT_VM0(); }   // last stage: nothing younger
      SCHED_FENCE();
      write_A(p ^ 1, (p == 0) ? xs1 : xs0);   // x(c+1) = slot[(c+1)&1]
      ASM_WAIT_LGKM();
      SCHED_FENCE();
      __builtin_amdgcn_s_barrier();
      SCHED_FENCE();
    }
  }

  // ---- Epilogue: outputs (v1 layout) ----
  const int strip = wave * 16;
#pragma unroll
  for (int j = 0; j < 12; ++j) {
    const int n  = j * 16 + l15;
    const int mm = n >> 6;
    const int h  = n & 63;
#pragma unroll
    for (int r = 0; r < 4; ++r) {
      const int trow = row0 + strip + l4 * 4 + r;
      const float val = acc[j][r];
      const __hip_bfloat16 hi = __float2bfloat16(val);
      const __hip_bfloat16 lo = __float2bfloat16(val - __bfloat162float(hi));
      if (mm == 0) {
        qhi[trow * 64 + h] = hi;
        qlo[trow * 64 + h] = lo;
      } else if (mm == 1) {
        khi[trow * 64 + h] = hi;
        klo[trow * 64 + h] = lo;
      } else {
        const int bb = trow >> 11, tl = trow & 2047;
        vT[(bb * 64 + h) * 2048 + tl] = hi;
      }
    }
  }

  // ---- Fused knorm: |k_row|^2 from acc[4..7] (k cols), per-wave rows ----
#pragma unroll
  for (int r = 0; r < 4; ++r) {
    float s2 = acc[4][r] * acc[4][r] + acc[5][r] * acc[5][r] +
               acc[6][r] * acc[6][r] + acc[7][r] * acc[7][r];
    s2 += __shfl_xor(s2, 1);
    s2 += __shfl_xor(s2, 2);
    s2 += __shfl_xor(s2, 4);
    s2 += __shfl_xor(s2, 8);            // sum over 16-lane col group (l15)
    if (l15 == 0) Ksm[wave][l4 * 4 + r] = s2;
  }
  __syncthreads();
  if (wave == 0) {
    float k2 = Ksm[lane >> 4][lane & 15];   // 64 lanes = block's 64 rows
#pragma unroll
    for (int off = 1; off < 64; off <<= 1) k2 = fmaxf(k2, __shfl_xor(k2, off));
    if (lane == 0)
      atomicMax((int*)&maxk2[row0 >> 11], __float_as_int(k2));
  }
}

// ---------------------------------------------------------------------------
// Kernel B v11 (unchanged): 32-row wave-tiles + in-wave pipeline + balanced
// strip map; bound-subtract softmax (no shuffles/rescale), MFMA row-sum L,
// plain-sum merge. lb(256,2) only.
// ---------------------------------------------------------------------------
__global__ __launch_bounds__(256, 2) void attn(
    const __hip_bfloat16* __restrict__ qhi, const __hip_bfloat16* __restrict__ qlo,
    const __hip_bfloat16* __restrict__ khi, const __hip_bfloat16* __restrict__ klo,
    const __hip_bfloat16* __restrict__ vT, const float* __restrict__ maxk2,
    float* __restrict__ out) {
  __shared__ __hip_bfloat16 Psm[4][2][16 * 72];  // per-wave, per-m P transpose
  __shared__ float Osm[4][32][65];               // per-wave partial O (fp32)
  __shared__ float Lsm[4][32];                   // per-wave partial L

  const int tid  = threadIdx.x;
  const int wave = tid >> 6;
  const int lane = tid & 63;
  const int l15 = lane & 15, l4 = lane >> 4;

  const int b = blockIdx.x & 7;              // XCD-local batch
  const int g = blockIdx.x >> 3;             // 0..63
  const int ss = (g < 32) ? (63 - g) : (g - 32);  // CU's 2 blocks sum ~const
  const int t0 = ss * 32;
  const int ntiles = (ss >> 1) + 1;          // causal 64-key tiles

  // ---- Q A-frags for 2 m sub-tiles, hi+lo (32 VGPRs) ----
  short8 qh0[2], qh1[2], ql0[2], ql1[2];
#pragma unroll
  for (int m = 0; m < 2; ++m) {
    const __hip_bfloat16* qph = qhi + (b * 2048 + t0 + m * 16 + l15) * 64;
    const __hip_bfloat16* qpl = qlo + (b * 2048 + t0 + m * 16 + l15) * 64;
    qh0[m] = *(const short8*)(qph + l4 * 8);
    qh1[m] = *(const short8*)(qph + 32 + l4 * 8);
    ql0[m] = *(const short8*)(qpl + l4 * 8);
    ql1[m] = *(const short8*)(qpl + 32 + l4 * 8);
  }

  // ---- per-row Cauchy-Schwarz bound c_r = |q_r| * kmax + 2 ----
  const float kmax = sqrtf(maxk2[b]);
  float c_[2][4];
#pragma unroll
  for (int m = 0; m < 2; ++m) {
    float qn = 0.f;
#pragma unroll
    for (int i = 0; i < 8; ++i) {
      const float v0 = bf2f(qh0[m][i]) + bf2f(ql0[m][i]);
      const float v1 = bf2f(qh1[m][i]) + bf2f(ql1[m][i]);
      qn += v0 * v0 + v1 * v1;
    }
    qn += __shfl_xor(qn, 16);
    qn += __shfl_xor(qn, 32);                // |q_{t0+m*16+l15}|^2
    const float crow = sqrtf(qn) * kmax + 2.0f;
#pragma unroll
    for (int r = 0; r < 4; ++r) c_[m][r] = __shfl(crow, l4 * 4 + r);
  }

  short8 ones;                                // bf16 1.0 x8 (B-frag for L)
#pragma unroll
  for (int i = 0; i < 8; ++i) ones[i] = (short)0x3F80;

  f32x4 acc[2][4];
#pragma unroll
  for (int m = 0; m < 2; ++m)
#pragma unroll
    for (int j = 0; j < 4; ++j) acc[m][j] = f32x4{0.f, 0.f, 0.f, 0.f};
  f32x4 accL[2];
  accL[0] = f32x4{0.f, 0.f, 0.f, 0.f};
  accL[1] = f32x4{0.f, 0.f, 0.f, 0.f};

  const __hip_bfloat16* kbase_h = khi + (size_t)b * 2048 * 64;
  const __hip_bfloat16* kbase_l = klo + (size_t)b * 2048 * 64;
  const __hip_bfloat16* vbase   = vT + (size_t)b * 64 * 2048;

  // K frags for the wave's CURRENT tile (reused as prefetch destination)
  short8 kh0[4], kh1[4], kl0[4], kl1[4];
  auto load_K = [&](int k0) {
#pragma unroll
    for (int j = 0; j < 4; ++j) {
      const __hip_bfloat16* kph = kbase_h + (k0 + j * 16 + l15) * 64;
      const __hip_bfloat16* kpl = kbase_l + (k0 + j * 16 + l15) * 64;
      kh0[j] = *(const short8*)(kph + l4 * 8);
      kh1[j] = *(const short8*)(kph + 32 + l4 * 8);
      kl0[j] = *(const short8*)(kpl + l4 * 8);
      kl1[j] = *(const short8*)(kpl + 32 + l4 * 8);
    }
  };

  if (wave < ntiles) load_K(wave << 6);      // prologue prefetch

  for (int kt = wave; kt < ntiles; kt += 4) {
    const int k0 = kt << 6;
    const bool diag = (kt == ntiles - 1);

    // ---- QK + softmax for m=0 (s dies before m=1's lives: caps regs) ----
    f32x4 s_[4];
#pragma unroll
    for (int m = 0; m < 2; ++m) {
      const int rowmax = t0 + m * 16 + 15;
#pragma unroll
      for (int j = 0; j < 4; ++j) {
        if (diag && (k0 + j * 16) > rowmax) {
          s_[j] = f32x4{-1e30f, -1e30f, -1e30f, -1e30f};
        } else {
          f32x4 z = f32x4{0.f, 0.f, 0.f, 0.f};
          z = mfma_16x16x32(qh0[m], kh0[j], z);
          z = mfma_16x16x32(qh1[m], kh1[j], z);
          z = mfma_16x16x32(qh0[m], kl0[j], z);
          z = mfma_16x16x32(qh1[m], kl1[j], z);
          z = mfma_16x16x32(ql0[m], kh0[j], z);
          z = mfma_16x16x32(ql1[m], kh1[j], z);
          s_[j] = z;
        }
      }
      if (m == 1) break;  // m=1: V + prefetch issued before its softmax below
      if (diag) {
#pragma unroll
        for (int j = 0; j < 4; ++j) {
          const int key = k0 + j * 16 + l15;
#pragma unroll
          for (int r = 0; r < 4; ++r)
            if (key > (t0 + l4 * 4 + r)) s_[j][r] = -1e30f;
        }
      }
#pragma unroll
      for (int j = 0; j < 4; ++j)
#pragma unroll
        for (int r = 0; r < 4; ++r) {
          const float pv = __expf(s_[j][r] - c_[0][r]);
          Psm[wave][0][(l4 * 4 + r) * 72 + j * 16 + l15] = __float2bfloat16(pv);
        }
    }

    // ---- V loads for this tile (latency hidden by m=1 softmax + P wait) ----
    short8 vf0[4], vf1[4];
#pragma unroll
    for (int j = 0; j < 4; ++j) {
      const __hip_bfloat16* vp = vbase + (j * 16 + l15) * 2048 + k0;
      vf0[j] = *(const short8*)(vp + l4 * 8);
      vf1[j] = *(const short8*)(vp + 32 + l4 * 8);
    }
    // ---- prefetch next tile's K (K regs free: QK done for both m) ----
    if (kt + 4 < ntiles) load_K((kt + 4) << 6);

    // ---- m=1 softmax (s_ holds m=1 scores) ----
    if (diag) {
#pragma unroll
      for (int j = 0; j < 4; ++j) {
        const int key = k0 + j * 16 + l15;
#pragma unroll
        for (int r = 0; r < 4; ++r)
          if (key > (t0 + 16 + l4 * 4 + r)) s_[j][r] = -1e30f;
      }
    }
#pragma unroll
    for (int j = 0; j < 4; ++j)
#pragma unroll
      for (int r = 0; r < 4; ++r) {
        const float pv = __expf(s_[j][r] - c_[1][r]);
        Psm[wave][1][(l4 * 4 + r) * 72 + j * 16 + l15] = __float2bfloat16(pv);
      }

    WAIT_LGKM0();   // all 32 P writes visible to same wave; vmcnt untouched

    // ---- O += P V ; L += P . 1 ----
#pragma unroll
    for (int m = 0; m < 2; ++m) {
      const short8 pf0 = *(const short8*)&Psm[wave][m][l15 * 72 + l4 * 8];
      const short8 pf1 = *(const short8*)&Psm[wave][m][l15 * 72 + 32 + l4 * 8];
#pragma unroll
      for (int j = 0; j < 4; ++j) {
        acc[m][j] = mfma_16x16x32(pf0, vf0[j], acc[m][j]);
        acc[m][j] = mfma_16x16x32(pf1, vf1[j], acc[m][j]);
      }
      accL[m] = mfma_16x16x32(pf0, ones, accL[m]);
      accL[m] = mfma_16x16x32(pf1, ones, accL[m]);
    }
  }

  // ---- per-wave partials into LDS (fp32, plain sums) ----
#pragma unroll
  for (int m = 0; m < 2; ++m) {
#pragma unroll
    for (int j = 0; j < 4; ++j)
#pragma unroll
      for (int r = 0; r < 4; ++r)
        Osm[wave][m * 16 + l4 * 4 + r][j * 16 + l15] = acc[m][j][r];
    if (l15 == 0) {
#pragma unroll
      for (int r = 0; r < 4; ++r)
        Lsm[wave][m * 16 + l4 * 4 + r] = accL[m][r];
    }
  }
  __syncthreads();

  // ---- cross-wave merge: PLAIN SUM (c_r uniform per row -> exact) ----
#pragma unroll
  for (int rr = 0; rr < 8; ++rr) {
    const int row = wave * 8 + rr;
    const float L = Lsm[0][row] + Lsm[1][row] + Lsm[2][row] + Lsm[3][row];
    const float O = Osm[0][row][lane] + Osm[1][row][lane] +
                    Osm[2][row][lane] + Osm[3][row][lane];
    out[(b * 2048 + t0 + row) * 64 + lane] = O / L;
  }
}

// ---------------------------------------------------------------------------
extern "C" void kernel_launch(void* const* d_in, const int* in_sizes, int n_in,
                              void* d_out, int out_size, void* d_ws, size_t ws_size,
                              hipStream_t stream) {
  const float* x  = (const float*)d_in[0];
  const float* Wq = (const float*)d_in[1];
  const float* Wk = (const float*)d_in[2];
  const float* Wv = (const float*)d_in[3];
  float* out = (float*)d_out;

  char* ws = (char*)d_ws;
  __hip_bfloat16* Wthi = (__hip_bfloat16*)ws;                   // 384 KB
  __hip_bfloat16* Wtlo = (__hip_bfloat16*)(ws + 393216);        // 384 KB
  __hip_bfloat16* qhi  = (__hip_bfloat16*)(ws + 786432);        // 2 MB each
  __hip_bfloat16* qlo  = (__hip_bfloat16*)(ws + 786432 + 1 * 2097152);
  __hip_bfloat16* khi  = (__hip_bfloat16*)(ws + 786432 + 2 * 2097152);
  __hip_bfloat16* klo  = (__hip_bfloat16*)(ws + 786432 + 3 * 2097152);
  __hip_bfloat16* vT   = (__hip_bfloat16*)(ws + 786432 + 4 * 2097152);
  float* maxk2         = (float*)(ws + 786432 + 5 * 2097152);   // 32 B

  prep_w<<<192, 256, 0, stream>>>(Wq, Wk, Wv, Wthi, Wtlo, maxk2);
  qkv_gemm<<<256, 256, 0, stream>>>(x, Wthi, Wtlo, qhi, qlo, khi, klo, vT, maxk2);
  attn<<<512, 256, 0, stream>>>(qhi, qlo, khi, klo, vT, maxk2, out);
}

// Round 12
// 148.637 us; speedup vs baseline: 1.2498x; 1.0057x over previous
//
#include <hip/hip_runtime.h>
#include <hip/hip_bf16.h>

// Problem constants
#define BB 8
#define TT 2048
#define EE 1024
#define HH 64

typedef __attribute__((ext_vector_type(8))) short short8;
typedef __attribute__((ext_vector_type(4))) float f32x4;

__device__ inline f32x4 mfma_16x16x32(short8 a, short8 b, f32x4 c) {
  return __builtin_amdgcn_mfma_f32_16x16x32_bf16(a, b, c, 0, 0, 0);
}

// async global->LDS, 16B per lane, LDS dest = wave-uniform base + lane*16
__device__ inline void gload_lds16(const __hip_bfloat16* g, __hip_bfloat16* l) {
  __builtin_amdgcn_global_load_lds((const __attribute__((address_space(1))) void*)g,
                                   (__attribute__((address_space(3))) void*)l,
                                   16, 0, 0);
}

__device__ inline short f2bf(float f) {
  __hip_bfloat16 h = __float2bfloat16(f);
  return *reinterpret_cast<short*>(&h);
}
__device__ inline float bf2f(short s) {
  __hip_bfloat16 h = *reinterpret_cast<__hip_bfloat16*>(&s);
  return __bfloat162float(h);
}

// wait lgkmcnt(0) only; leave vmcnt/expcnt unconstrained
#define WAIT_LGKM0() __builtin_amdgcn_s_waitcnt(0xC07F)
#define SCHED_FENCE() __builtin_amdgcn_sched_barrier(0)
// counted waits (inline asm: compiler must not widen them to vmcnt(0))
#define ASM_WAIT_VM4()  asm volatile("s_waitcnt vmcnt(4)" ::: "memory")
#define ASM_WAIT_VM0()  asm volatile("s_waitcnt vmcnt(0)" ::: "memory")

// ---------------------------------------------------------------------------
// Kernel 0: split-precision transposed weights. Block 0 also zeroes maxk2.
// ---------------------------------------------------------------------------
__global__ void prep_w(const float* __restrict__ Wq, const float* __restrict__ Wk,
                       const float* __restrict__ Wv,
                       __hip_bfloat16* __restrict__ Wthi,
                       __hip_bfloat16* __restrict__ Wtlo,
                       float* __restrict__ maxk2) {
  const int n = blockIdx.x;          // 0..191
  if (n == 0 && threadIdx.x < 8) maxk2[threadIdx.x] = 0.f;
  const int m = n >> 6;
  const int h = n & 63;
  const float* W = (m == 0) ? Wq : (m == 1) ? Wk : Wv;
  const int e0 = threadIdx.x * 4;    // 256 threads * 4 = 1024
#pragma unroll
  for (int j = 0; j < 4; ++j) {
    const float w = W[(e0 + j) * 64 + h];
    const __hip_bfloat16 hi = __float2bfloat16(w);
    Wthi[n * 1024 + e0 + j] = hi;
    Wtlo[n * 1024 + e0 + j] = __float2bfloat16(w - __bfloat162float(hi));
  }
}

// ---------------------------------------------------------------------------
// Kernel A v6: A-in-registers + B-only LDS (exactly 2 blocks/CU).
// Insight from v5's dataflow: write_A was WAVE-LOCAL (wave w writes rows
// w*16..+15, compute reads exactly those) -> the A LDS round-trip + its
// lgkmcnt(0) were pure overhead. Now: per chunk each lane loads its 16
// x-floats in COMPUTE layout (row wave*16+l15, cols c*64+l4*8{,+32}) and
// converts hi/lo in regs. LDS = Bhi(192x64)+Blo(128x64) dbuf = 81920 B =
// exactly half of 160KiB -> 2 blocks/CU (v1/v5: 1). Ksm aliases Bsm[0]
// (chunk 15 reads Bsm[1] only). Counted-vmcnt discipline from v5 kept:
// issue {B(c+1), x(c+2)}; compute; vmcnt(4) keeps x(c+2) in flight across
// the raw barrier; c=14 edge vmcnt(0). Convert A(c) BEFORE x(c+2)
// overwrites its slot (WAR). Not the v3 reg-direct trap: B still streams
// via global_load_lds+barrier; A-regs are 16 VGPR consumed per chunk.
// ---------------------------------------------------------------------------
__global__ __launch_bounds__(256) void qkv_gemm(
    const float* __restrict__ x,
    const __hip_bfloat16* __restrict__ Wthi, const __hip_bfloat16* __restrict__ Wtlo,
    __hip_bfloat16* __restrict__ qhi, __hip_bfloat16* __restrict__ qlo,
    __hip_bfloat16* __restrict__ khi, __hip_bfloat16* __restrict__ klo,
    __hip_bfloat16* __restrict__ vT, float* __restrict__ maxk2) {
  __shared__ __hip_bfloat16 Bsm[2][320 * 64];   // [buf][hi:192*64 | lo:128*64]
  float* Ksm = (float*)&Bsm[0][0];              // aliased after main loop

  const int tid  = threadIdx.x;
  const int wave = tid >> 6;
  const int lane = tid & 63;
  const int row0 = blockIdx.x * 64;
  const int l15 = lane & 15, l4 = lane >> 4;

  // A source in compute layout: row = wave*16+l15, col base = l4*8
  const float* xA = x + (size_t)(row0 + wave * 16 + l15) * 1024 + l4 * 8;

  f32x4 acc[12];
#pragma unroll
  for (int j = 0; j < 12; ++j) acc[j] = f32x4{0.f, 0.f, 0.f, 0.f};

  auto issue_B = [&](int c, int buf) {
    const int g = (lane & 7) ^ ((lane >> 3) & 7);
#pragma unroll
    for (int s = 0; s < 6; ++s) {
      const int qq = wave * 6 + s;
      const int n  = qq * 8 + (lane >> 3);
      gload_lds16(Wthi + n * 1024 + c * 64 + g * 8, &Bsm[buf][qq * 512]);
      if (qq < 16)
        gload_lds16(Wtlo + n * 1024 + c * 64 + g * 8, &Bsm[buf][192 * 64 + qq * 512]);
    }
  };
  auto load_x = [&](int c, f32x4* sl) {
    const f32x4* p0 = (const f32x4*)(xA + c * 64);
    const f32x4* p1 = (const f32x4*)(xA + c * 64 + 32);
    sl[0] = p0[0]; sl[1] = p0[1]; sl[2] = p1[0]; sl[3] = p1[1];
  };
  auto convert_A = [&](const f32x4* sp, short8& ah0, short8& ah1,
                       short8& al0, short8& al1) {
    const float* xf = (const float*)sp;
#pragma unroll
    for (int i = 0; i < 8; ++i) {
      const float v = xf[i];
      const short h = f2bf(v);
      ah0[i] = h;
      al0[i] = f2bf(v - bf2f(h));
    }
#pragma unroll
    for (int i = 0; i < 8; ++i) {
      const float v = xf[8 + i];
      const short h = f2bf(v);
      ah1[i] = h;
      al1[i] = f2bf(v - bf2f(h));
    }
  };
  auto compute = [&](int buf, const short8& ah0, const short8& ah1,
                     const short8& al0, const short8& al1) {
    const __hip_bfloat16* Bh = &Bsm[buf][0];
    const __hip_bfloat16* Bl = &Bsm[buf][192 * 64];
#pragma unroll
    for (int j = 0; j < 12; ++j) {
      const int n  = j * 16 + l15;
      const int o0 = ((l4)     ^ (n & 7)) * 8;
      const int o1 = ((4 + l4) ^ (n & 7)) * 8;
      short8 bh0 = *(const short8*)&Bh[n * 64 + o0];
      short8 bh1 = *(const short8*)&Bh[n * 64 + o1];
      acc[j] = mfma_16x16x32(ah0, bh0, acc[j]);
      acc[j] = mfma_16x16x32(ah1, bh1, acc[j]);
      if (j < 8) {
        short8 bl0 = *(const short8*)&Bl[n * 64 + o0];
        short8 bl1 = *(const short8*)&Bl[n * 64 + o1];
        acc[j] = mfma_16x16x32(ah0, bl0, acc[j]);
        acc[j] = mfma_16x16x32(ah1, bl1, acc[j]);
        acc[j] = mfma_16x16x32(al0, bh0, acc[j]);
        acc[j] = mfma_16x16x32(al1, bh1, acc[j]);
      }
    }
  };

  // ---- Prologue: x(0)->xs0, B(0), x(1)->xs1; drain all but x(1) ----
  f32x4 xs0[4], xs1[4];
  load_x(0, xs0);
  issue_B(0, 0);
  load_x(1, xs1);
  ASM_WAIT_VM4();          // youngest 4 = x(1); drains x(0)+B(0)
  SCHED_FENCE();
  __builtin_amdgcn_s_barrier();
  SCHED_FENCE();

#pragma unroll
  for (int c = 0; c < 16; ++c) {
    const int p = c & 1;
    short8 ah0, ah1, al0, al1;
    convert_A((p == 0) ? xs0 : xs1, ah0, ah1, al0, al1);  // consume x(c) first
    if (c < 15) issue_B(c + 1, p ^ 1);
    if (c < 14) load_x(c + 2, (p == 0) ? xs0 : xs1);      // overwrite slot p
    SCHED_FENCE();        // loads issue before the MFMA body
    compute(p, ah0, ah1, al0, al1);
    if (c < 15) {
      if (c < 14) { ASM_WAIT_VM4(); }   // drain B(c+1)+x(c+1); keep x(c+2)
      else        { ASM_WAIT_VM0(); }   // c=14: no x(16) exists
      SCHED_FENCE();
      __builtin_amdgcn_s_barrier();
      SCHED_FENCE();
    }
  }

  // ---- Epilogue: outputs (v1 layout) ----
  const int strip = wave * 16;
#pragma unroll
  for (int j = 0; j < 12; ++j) {
    const int n  = j * 16 + l15;
    const int mm = n >> 6;
    const int h  = n & 63;
#pragma unroll
    for (int r = 0; r < 4; ++r) {
      const int trow = row0 + strip + l4 * 4 + r;
      const float val = acc[j][r];
      const __hip_bfloat16 hi = __float2bfloat16(val);
      const __hip_bfloat16 lo = __float2bfloat16(val - __bfloat162float(hi));
      if (mm == 0) {
        qhi[trow * 64 + h] = hi;
        qlo[trow * 64 + h] = lo;
      } else if (mm == 1) {
        khi[trow * 64 + h] = hi;
        klo[trow * 64 + h] = lo;
      } else {
        const int bb = trow >> 11, tl = trow & 2047;
        vT[(bb * 64 + h) * 2048 + tl] = hi;
      }
    }
  }

  // ---- Fused knorm: |k_row|^2 from acc[4..7]; Ksm aliases Bsm[0] (chunk 15
  // read Bsm[1] only, so no residual readers of these bytes) ----
#pragma unroll
  for (int r = 0; r < 4; ++r) {
    float s2 = acc[4][r] * acc[4][r] + acc[5][r] * acc[5][r] +
               acc[6][r] * acc[6][r] + acc[7][r] * acc[7][r];
    s2 += __shfl_xor(s2, 1);
    s2 += __shfl_xor(s2, 2);
    s2 += __shfl_xor(s2, 4);
    s2 += __shfl_xor(s2, 8);            // sum over 16-lane col group (l15)
    if (l15 == 0) Ksm[wave * 16 + l4 * 4 + r] = s2;
  }
  __syncthreads();
  if (wave == 0) {
    float k2 = Ksm[lane];               // lane = w*16+row exactly
#pragma unroll
    for (int off = 1; off < 64; off <<= 1) k2 = fmaxf(k2, __shfl_xor(k2, off));
    if (lane == 0)
      atomicMax((int*)&maxk2[row0 >> 11], __float_as_int(k2));
  }
}

// ---------------------------------------------------------------------------
// Kernel B v11 (unchanged): 32-row wave-tiles + in-wave pipeline + balanced
// strip map; bound-subtract softmax (no shuffles/rescale), MFMA row-sum L,
// plain-sum merge. lb(256,2) only.
// ---------------------------------------------------------------------------
__global__ __launch_bounds__(256, 2) void attn(
    const __hip_bfloat16* __restrict__ qhi, const __hip_bfloat16* __restrict__ qlo,
    const __hip_bfloat16* __restrict__ khi, const __hip_bfloat16* __restrict__ klo,
    const __hip_bfloat16* __restrict__ vT, const float* __restrict__ maxk2,
    float* __restrict__ out) {
  __shared__ __hip_bfloat16 Psm[4][2][16 * 72];  // per-wave, per-m P transpose
  __shared__ float Osm[4][32][65];               // per-wave partial O (fp32)
  __shared__ float Lsm[4][32];                   // per-wave partial L

  const int tid  = threadIdx.x;
  const int wave = tid >> 6;
  const int lane = tid & 63;
  const int l15 = lane & 15, l4 = lane >> 4;

  const int b = blockIdx.x & 7;              // XCD-local batch
  const int g = blockIdx.x >> 3;             // 0..63
  const int ss = (g < 32) ? (63 - g) : (g - 32);  // CU's 2 blocks sum ~const
  const int t0 = ss * 32;
  const int ntiles = (ss >> 1) + 1;          // causal 64-key tiles

  // ---- Q A-frags for 2 m sub-tiles, hi+lo (32 VGPRs) ----
  short8 qh0[2], qh1[2], ql0[2], ql1[2];
#pragma unroll
  for (int m = 0; m < 2; ++m) {
    const __hip_bfloat16* qph = qhi + (b * 2048 + t0 + m * 16 + l15) * 64;
    const __hip_bfloat16* qpl = qlo + (b * 2048 + t0 + m * 16 + l15) * 64;
    qh0[m] = *(const short8*)(qph + l4 * 8);
    qh1[m] = *(const short8*)(qph + 32 + l4 * 8);
    ql0[m] = *(const short8*)(qpl + l4 * 8);
    ql1[m] = *(const short8*)(qpl + 32 + l4 * 8);
  }

  // ---- per-row Cauchy-Schwarz bound c_r = |q_r| * kmax + 2 ----
  const float kmax = sqrtf(maxk2[b]);
  float c_[2][4];
#pragma unroll
  for (int m = 0; m < 2; ++m) {
    float qn = 0.f;
#pragma unroll
    for (int i = 0; i < 8; ++i) {
      const float v0 = bf2f(qh0[m][i]) + bf2f(ql0[m][i]);
      const float v1 = bf2f(qh1[m][i]) + bf2f(ql1[m][i]);
      qn += v0 * v0 + v1 * v1;
    }
    qn += __shfl_xor(qn, 16);
    qn += __shfl_xor(qn, 32);                // |q_{t0+m*16+l15}|^2
    const float crow = sqrtf(qn) * kmax + 2.0f;
#pragma unroll
    for (int r = 0; r < 4; ++r) c_[m][r] = __shfl(crow, l4 * 4 + r);
  }

  short8 ones;                                // bf16 1.0 x8 (B-frag for L)
#pragma unroll
  for (int i = 0; i < 8; ++i) ones[i] = (short)0x3F80;

  f32x4 acc[2][4];
#pragma unroll
  for (int m = 0; m < 2; ++m)
#pragma unroll
    for (int j = 0; j < 4; ++j) acc[m][j] = f32x4{0.f, 0.f, 0.f, 0.f};
  f32x4 accL[2];
  accL[0] = f32x4{0.f, 0.f, 0.f, 0.f};
  accL[1] = f32x4{0.f, 0.f, 0.f, 0.f};

  const __hip_bfloat16* kbase_h = khi + (size_t)b * 2048 * 64;
  const __hip_bfloat16* kbase_l = klo + (size_t)b * 2048 * 64;
  const __hip_bfloat16* vbase   = vT + (size_t)b * 64 * 2048;

  // K frags for the wave's CURRENT tile (reused as prefetch destination)
  short8 kh0[4], kh1[4], kl0[4], kl1[4];
  auto load_K = [&](int k0) {
#pragma unroll
    for (int j = 0; j < 4; ++j) {
      const __hip_bfloat16* kph = kbase_h + (k0 + j * 16 + l15) * 64;
      const __hip_bfloat16* kpl = kbase_l + (k0 + j * 16 + l15) * 64;
      kh0[j] = *(const short8*)(kph + l4 * 8);
      kh1[j] = *(const short8*)(kph + 32 + l4 * 8);
      kl0[j] = *(const short8*)(kpl + l4 * 8);
      kl1[j] = *(const short8*)(kpl + 32 + l4 * 8);
    }
  };

  if (wave < ntiles) load_K(wave << 6);      // prologue prefetch

  for (int kt = wave; kt < ntiles; kt += 4) {
    const int k0 = kt << 6;
    const bool diag = (kt == ntiles - 1);

    // ---- QK + softmax for m=0 (s dies before m=1's lives: caps regs) ----
    f32x4 s_[4];
#pragma unroll
    for (int m = 0; m < 2; ++m) {
      const int rowmax = t0 + m * 16 + 15;
#pragma unroll
      for (int j = 0; j < 4; ++j) {
        if (diag && (k0 + j * 16) > rowmax) {
          s_[j] = f32x4{-1e30f, -1e30f, -1e30f, -1e30f};
        } else {
          f32x4 z = f32x4{0.f, 0.f, 0.f, 0.f};
          z = mfma_16x16x32(qh0[m], kh0[j], z);
          z = mfma_16x16x32(qh1[m], kh1[j], z);
          z = mfma_16x16x32(qh0[m], kl0[j], z);
          z = mfma_16x16x32(qh1[m], kl1[j], z);
          z = mfma_16x16x32(ql0[m], kh0[j], z);
          z = mfma_16x16x32(ql1[m], kh1[j], z);
          s_[j] = z;
        }
      }
      if (m == 1) break;  // m=1: V + prefetch issued before its softmax below
      if (diag) {
#pragma unroll
        for (int j = 0; j < 4; ++j) {
          const int key = k0 + j * 16 + l15;
#pragma unroll
          for (int r = 0; r < 4; ++r)
            if (key > (t0 + l4 * 4 + r)) s_[j][r] = -1e30f;
        }
      }
#pragma unroll
      for (int j = 0; j < 4; ++j)
#pragma unroll
        for (int r = 0; r < 4; ++r) {
          const float pv = __expf(s_[j][r] - c_[0][r]);
          Psm[wave][0][(l4 * 4 + r) * 72 + j * 16 + l15] = __float2bfloat16(pv);
        }
    }

    // ---- V loads for this tile (latency hidden by m=1 softmax + P wait) ----
    short8 vf0[4], vf1[4];
#pragma unroll
    for (int j = 0; j < 4; ++j) {
      const __hip_bfloat16* vp = vbase + (j * 16 + l15) * 2048 + k0;
      vf0[j] = *(const short8*)(vp + l4 * 8);
      vf1[j] = *(const short8*)(vp + 32 + l4 * 8);
    }
    // ---- prefetch next tile's K (K regs free: QK done for both m) ----
    if (kt + 4 < ntiles) load_K((kt + 4) << 6);

    // ---- m=1 softmax (s_ holds m=1 scores) ----
    if (diag) {
#pragma unroll
      for (int j = 0; j < 4; ++j) {
        const int key = k0 + j * 16 + l15;
#pragma unroll
        for (int r = 0; r < 4; ++r)
          if (key > (t0 + 16 + l4 * 4 + r)) s_[j][r] = -1e30f;
      }
    }
#pragma unroll
    for (int j = 0; j < 4; ++j)
#pragma unroll
      for (int r = 0; r < 4; ++r) {
        const float pv = __expf(s_[j][r] - c_[1][r]);
        Psm[wave][1][(l4 * 4 + r) * 72 + j * 16 + l15] = __float2bfloat16(pv);
      }

    WAIT_LGKM0();   // all 32 P writes visible to same wave; vmcnt untouched

    // ---- O += P V ; L += P . 1 ----
#pragma unroll
    for (int m = 0; m < 2; ++m) {
      const short8 pf0 = *(const short8*)&Psm[wave][m][l15 * 72 + l4 * 8];
      const short8 pf1 = *(const short8*)&Psm[wave][m][l15 * 72 + 32 + l4 * 8];
#pragma unroll
      for (int j = 0; j < 4; ++j) {
        acc[m][j] = mfma_16x16x32(pf0, vf0[j], acc[m][j]);
        acc[m][j] = mfma_16x16x32(pf1, vf1[j], acc[m][j]);
      }
      accL[m] = mfma_16x16x32(pf0, ones, accL[m]);
      accL[m] = mfma_16x16x32(pf1, ones, accL[m]);
    }
  }

  // ---- per-wave partials into LDS (fp32, plain sums) ----
#pragma unroll
  for (int m = 0; m < 2; ++m) {
#pragma unroll
    for (int j = 0; j < 4; ++j)
#pragma unroll
      for (int r = 0; r < 4; ++r)
        Osm[wave][m * 16 + l4 * 4 + r][j * 16 + l15] = acc[m][j][r];
    if (l15 == 0) {
#pragma unroll
      for (int r = 0; r < 4; ++r)
        Lsm[wave][m * 16 + l4 * 4 + r] = accL[m][r];
    }
  }
  __syncthreads();

  // ---- cross-wave merge: PLAIN SUM (c_r uniform per row -> exact) ----
#pragma unroll
  for (int rr = 0; rr < 8; ++rr) {
    const int row = wave * 8 + rr;
    const float L = Lsm[0][row] + Lsm[1][row] + Lsm[2][row] + Lsm[3][row];
    const float O = Osm[0][row][lane] + Osm[1][row][lane] +
                    Osm[2][row][lane] + Osm[3][row][lane];
    out[(b * 2048 + t0 + row) * 64 + lane] = O / L;
  }
}

// ---------------------------------------------------------------------------
extern "C" void kernel_launch(void* const* d_in, const int* in_sizes, int n_in,
                              void* d_out, int out_size, void* d_ws, size_t ws_size,
                              hipStream_t stream) {
  const float* x  = (const float*)d_in[0];
  const float* Wq = (const float*)d_in[1];
  const float* Wk = (const float*)d_in[2];
  const float* Wv = (const float*)d_in[3];
  float* out = (float*)d_out;

  char* ws = (char*)d_ws;
  __hip_bfloat16* Wthi = (__hip_bfloat16*)ws;                   // 384 KB
  __hip_bfloat16* Wtlo = (__hip_bfloat16*)(ws + 393216);        // 384 KB
  __hip_bfloat16* qhi  = (__hip_bfloat16*)(ws + 786432);        // 2 MB each
  __hip_bfloat16* qlo  = (__hip_bfloat16*)(ws + 786432 + 1 * 2097152);
  __hip_bfloat16* khi  = (__hip_bfloat16*)(ws + 786432 + 2 * 2097152);
  __hip_bfloat16* klo  = (__hip_bfloat16*)(ws + 786432 + 3 * 2097152);
  __hip_bfloat16* vT   = (__hip_bfloat16*)(ws + 786432 + 4 * 2097152);
  float* maxk2         = (float*)(ws + 786432 + 5 * 2097152);   // 32 B

  prep_w<<<192, 256, 0, stream>>>(Wq, Wk, Wv, Wthi, Wtlo, maxk2);
  qkv_gemm<<<256, 256, 0, stream>>>(x, Wthi, Wtlo, qhi, qlo, khi, klo, vT, maxk2);
  attn<<<512, 256, 0, stream>>>(qhi, qlo, khi, klo, vT, maxk2, out);
}